// Round 17
// baseline (377.276 us; speedup 1.0000x reference)
//
#include <hip/hip_runtime.h>

#define NN 50000
#define NE 600000
#define HD 128
#define OUTF 64
#define NL 4
#define NG 128
#define BN_EPS 1e-5f
#define NSB 196   // ceil(NN/256) scan blocks

typedef __attribute__((ext_vector_type(8))) short short8v;
typedef __attribute__((ext_vector_type(4))) float float4v;

#define LDSW 136   // padded LDS row stride in bf16 elems
#define TR 48      // layer tile rows -> grid 1042 (~4.07 blocks/CU, 32-wave cap)

__device__ inline unsigned short f2bf(float f) {   // RNE f32->bf16 (finite inputs)
    unsigned int u = __float_as_uint(f);
    return (unsigned short)((u + 0x7FFF + ((u >> 16) & 1)) >> 16);
}
__device__ inline float bf2f(short s) {
    return __uint_as_float(((unsigned int)(unsigned short)s) << 16);
}

// ---------------------------------------------------------------------------
// W pre-pack + stats zero + deg zero: wpack[w][nt][kb][lane][i].
// ---------------------------------------------------------------------------
__global__ __launch_bounds__(256) void pack_w_kernel(
    const float* __restrict__ W1, const float* __restrict__ W2,
    short* __restrict__ wpack, float* __restrict__ stats4, int* __restrict__ deg)
{
    int gid = blockIdx.x * 256 + threadIdx.x;    // 8*8*4*64 = 16384
    if (gid < 256)
        reinterpret_cast<float4*>(stats4)[gid] = (float4){0.f, 0.f, 0.f, 0.f};
    if (gid < 12500)   // NN/4 exactly
        reinterpret_cast<int4*>(deg)[gid] = (int4){0, 0, 0, 0};
    int l  = gid & 63;
    int kb = (gid >> 6) & 3;
    int nt = (gid >> 8) & 7;
    int w  = gid >> 11;                          // 0..7
    const float* W = (w & 1) ? (W2 + (size_t)(w >> 1) * HD * HD)
                             : (W1 + (size_t)(w >> 1) * HD * HD);
    int col  = nt * 16 + (l & 15);
    int krow = kb * 32 + (l >> 4) * 8;
    short* o = wpack + (size_t)w * 16384 + ((size_t)(nt * 4 + kb) * 64 + l) * 8;
    #pragma unroll
    for (int i = 0; i < 8; i++)
        o[i] = (short)f2bf(W[(size_t)(krow + i) * HD + col]);
}

// x (f32) -> hb (bf16), one-time.
__global__ __launch_bounds__(256) void cvt_bf16_kernel(
    const float* __restrict__ x, short* __restrict__ hb)
{
    int idx = blockIdx.x * 256 + threadIdx.x;
    if (idx >= NN * 32) return;
    float4 v = reinterpret_cast<const float4*>(x)[idx];
    short4 o = make_short4((short)f2bf(v.x), (short)f2bf(v.y),
                           (short)f2bf(v.z), (short)f2bf(v.w));
    reinterpret_cast<short4*>(hb)[idx] = o;
}

// ---------------------------------------------------------------------------
// Fused GIN layer kernel, 48-row tile, 512 threads (8 waves).
// Gather body is the R13/R16 known-good 2-deep unroll; BN on the fly.
// MFMA phases: 6 active waves (3 row-blocks x 2 col-halves); wv 6,7 idle.
// ---------------------------------------------------------------------------
template<bool BN>
__global__ __launch_bounds__(512) void layer_kernel(
    const short* __restrict__ inb, const float* __restrict__ stats_prev,
    const float* __restrict__ gamma_p, const float* __restrict__ beta_p,
    const int* __restrict__ row_ptr, const int* __restrict__ csr,
    const short* __restrict__ wp1, const float* __restrict__ b1,
    const short* __restrict__ wp2, const float* __restrict__ b2,
    short* __restrict__ Cb, float* __restrict__ sums, float* __restrict__ sumsq)
{
    __shared__ __align__(16) short As[TR * LDSW];   // 13056 B
    __shared__ float sscale[HD];
    __shared__ float sshift[HD];
    const int t = threadIdx.x;
    const int row0 = blockIdx.x * TR;

    float sc[8], sh[8];
    const int c8 = (t & 15) * 8;
    if (BN) {
        if (t < HD) {
            const float invN = 1.f / (float)NN;
            float mean = stats_prev[t] * invN;
            float var = stats_prev[HD + t] * invN - mean * mean;
            float inv = rsqrtf(var + BN_EPS);
            float s = gamma_p[t] * inv;
            sscale[t] = s;
            sshift[t] = beta_p[t] - mean * s;
        }
        __syncthreads();
        #pragma unroll
        for (int i = 0; i < 8; i++) { sc[i] = sscale[c8 + i]; sh[i] = sshift[c8 + i]; }
    }

    // ---- 1) gather: 16 lanes/node, 32 nodes/iter; rows 0..47 ----
    {
        const int ng = t >> 4;          // 0..31
        #pragma unroll
        for (int it = 0; it < 2; it++) {
            int lr = it * 32 + ng;
            if (lr < TR) {
                int n = row0 + lr;
                float acc[8] = {0, 0, 0, 0, 0, 0, 0, 0};
                if (n < NN) {
                    short8v s = *reinterpret_cast<const short8v*>(&inb[(size_t)n * HD + c8]);
                    #pragma unroll
                    for (int i = 0; i < 8; i++)
                        acc[i] = BN ? fmaxf(bf2f(s[i]) * sc[i] + sh[i], 0.f) : bf2f(s[i]);
                    int p = row_ptr[n], pe = row_ptr[n + 1];
                    for (; p + 2 <= pe; p += 2) {
                        int s0 = csr[p], s1 = csr[p + 1];
                        short8v a = *reinterpret_cast<const short8v*>(&inb[(size_t)s0 * HD + c8]);
                        short8v b = *reinterpret_cast<const short8v*>(&inb[(size_t)s1 * HD + c8]);
                        if (BN) {
                            #pragma unroll
                            for (int i = 0; i < 8; i++)
                                acc[i] += fmaxf(bf2f(a[i]) * sc[i] + sh[i], 0.f)
                                        + fmaxf(bf2f(b[i]) * sc[i] + sh[i], 0.f);
                        } else {
                            #pragma unroll
                            for (int i = 0; i < 8; i++) acc[i] += bf2f(a[i]) + bf2f(b[i]);
                        }
                    }
                    if (p < pe) {
                        short8v a = *reinterpret_cast<const short8v*>(&inb[(size_t)csr[p] * HD + c8]);
                        #pragma unroll
                        for (int i = 0; i < 8; i++)
                            acc[i] += BN ? fmaxf(bf2f(a[i]) * sc[i] + sh[i], 0.f) : bf2f(a[i]);
                    }
                }
                short8v o;
                #pragma unroll
                for (int i = 0; i < 8; i++) o[i] = (short)f2bf(acc[i]);
                *reinterpret_cast<short8v*>(&As[lr * LDSW + c8]) = o;
            }
        }
    }
    __syncthreads();

    const int wv = t >> 6, l = t & 63;   // wv 0..7; wv 6,7 idle in MFMA
    const int l16 = l & 15, lhi = l >> 4;
    const int wrow = (wv >> 1) * 16;     // 0,16,32,(48 unused)
    const int nc0 = (wv & 1) * 4;        // 0 or 4
    const bool act = (wv < 6);

    // ---- 2) MFMA1 ----
    short8v a[4];
    if (act) {
        #pragma unroll
        for (int kb = 0; kb < 4; kb++)
            a[kb] = *reinterpret_cast<const short8v*>(&As[(wrow + l16) * LDSW + kb * 32 + lhi * 8]);
    }
    __syncthreads();   // a1-frags in regs; As free for mid

    float4v acc[4];
    #pragma unroll
    for (int q = 0; q < 4; q++) acc[q] = (float4v){0.f, 0.f, 0.f, 0.f};
    if (act) {
        const short8v* wp = reinterpret_cast<const short8v*>(wp1);
        #pragma unroll
        for (int q = 0; q < 4; q++) {
            int nt = nc0 + q;
            #pragma unroll
            for (int kb = 0; kb < 4; kb++) {
                short8v b = wp[(nt * 4 + kb) * 64 + l];
                acc[q] = __builtin_amdgcn_mfma_f32_16x16x32_bf16(a[kb], b, acc[q], 0, 0, 0);
            }
        }
        // relu + bf16 -> mid tile back into As
        #pragma unroll
        for (int q = 0; q < 4; q++) {
            int nt = nc0 + q;
            float bnt = b1[nt * 16 + l16];
            #pragma unroll
            for (int j = 0; j < 4; j++) {
                float v = fmaxf(acc[q][j] + bnt, 0.f);
                As[(wrow + lhi * 4 + j) * LDSW + nt * 16 + l16] = (short)f2bf(v);
            }
        }
    }
    __syncthreads();

    // ---- 3) MFMA2 ----
    if (act) {
        #pragma unroll
        for (int kb = 0; kb < 4; kb++)
            a[kb] = *reinterpret_cast<const short8v*>(&As[(wrow + l16) * LDSW + kb * 32 + lhi * 8]);
        #pragma unroll
        for (int q = 0; q < 4; q++) acc[q] = (float4v){0.f, 0.f, 0.f, 0.f};
        const short8v* wp = reinterpret_cast<const short8v*>(wp2);
        #pragma unroll
        for (int q = 0; q < 4; q++) {
            int nt = nc0 + q;
            #pragma unroll
            for (int kb = 0; kb < 4; kb++) {
                short8v b = wp[(nt * 4 + kb) * 64 + l];
                acc[q] = __builtin_amdgcn_mfma_f32_16x16x32_bf16(a[kb], b, acc[q], 0, 0, 0);
            }
        }
    }

    // epilogue: bf16 Cb + per-column stats (reuse As as f32 scratch)
    __syncthreads();   // mid reads done; As free for reduction
    float* redS = reinterpret_cast<float*>(As);          // [3][128]
    float* redQ = redS + 3 * HD;                         // [3][128]
    if (act) {
        #pragma unroll
        for (int q = 0; q < 4; q++) {
            int nt = nc0 + q;
            float bnt = b2[nt * 16 + l16];
            float snt = 0.f, qnt = 0.f;
            #pragma unroll
            for (int j = 0; j < 4; j++) {
                int r = row0 + wrow + lhi * 4 + j;
                if (r < NN) {
                    float v = acc[q][j] + bnt;
                    Cb[(size_t)r * HD + nt * 16 + l16] = (short)f2bf(v);
                    snt += v; qnt += v * v;
                }
            }
            snt += __shfl_xor(snt, 16); snt += __shfl_xor(snt, 32);
            qnt += __shfl_xor(qnt, 16); qnt += __shfl_xor(qnt, 32);
            if (lhi == 0) {
                redS[(wv >> 1) * HD + nt * 16 + l16] = snt;
                redQ[(wv >> 1) * HD + nt * 16 + l16] = qnt;
            }
        }
    }
    __syncthreads();
    if (t < HD) {
        float ss = redS[0 * HD + t] + redS[1 * HD + t] + redS[2 * HD + t];
        float qq = redQ[0 * HD + t] + redQ[1 * HD + t] + redQ[2 * HD + t];
        atomicAdd(&sums[t], ss);
        atomicAdd(&sumsq[t], qq);
    }
}

// ---------------------------------------------------------------------------
// CSR build: degree histogram -> 3-kernel parallel scan -> slot fill.
// ---------------------------------------------------------------------------
__global__ __launch_bounds__(256) void deg_hist_kernel(
    const int* __restrict__ dst, int* __restrict__ deg)
{
    int e = blockIdx.x * 256 + threadIdx.x;
    if (e < NE) atomicAdd(&deg[dst[e]], 1);
}

__global__ __launch_bounds__(256) void scan_partial_kernel(
    const int* __restrict__ deg, int* __restrict__ bsum)
{
    __shared__ int sd[256];
    int t = threadIdx.x;
    int i = blockIdx.x * 256 + t;
    sd[t] = (i < NN) ? deg[i] : 0;
    __syncthreads();
    for (int o = 128; o > 0; o >>= 1) {
        if (t < o) sd[t] += sd[t + o];
        __syncthreads();
    }
    if (t == 0) bsum[blockIdx.x] = sd[0];
}

__global__ __launch_bounds__(256) void scan_bsums_kernel(
    const int* __restrict__ bsum, int* __restrict__ boff)
{
    __shared__ int sd[256];
    int t = threadIdx.x;
    int v = (t < NSB) ? bsum[t] : 0;
    sd[t] = v;
    __syncthreads();
    for (int o = 1; o < 256; o <<= 1) {
        int x = (t >= o) ? sd[t - o] : 0;
        __syncthreads();
        sd[t] += x;
        __syncthreads();
    }
    if (t < NSB) boff[t] = sd[t] - v;   // exclusive
}

__global__ __launch_bounds__(256) void scan_final_kernel(
    const int* __restrict__ deg, const int* __restrict__ boff,
    int* __restrict__ row_ptr, int* __restrict__ cursor)
{
    __shared__ int sd[256];
    int t = threadIdx.x;
    int i = blockIdx.x * 256 + t;
    int v = (i < NN) ? deg[i] : 0;
    sd[t] = v;
    __syncthreads();
    for (int o = 1; o < 256; o <<= 1) {
        int x = (t >= o) ? sd[t - o] : 0;
        __syncthreads();
        sd[t] += x;
        __syncthreads();
    }
    int excl = sd[t] - v + boff[blockIdx.x];
    if (i < NN) { row_ptr[i] = excl; cursor[i] = excl; }
    if (i == NN - 1) row_ptr[NN] = excl + v;   // == NE
}

__global__ __launch_bounds__(256) void fill_csr_kernel(
    const int* __restrict__ src, const int* __restrict__ dst,
    int* __restrict__ cursor, int* __restrict__ csr)
{
    int e = blockIdx.x * 256 + threadIdx.x;
    if (e >= NE) return;
    int p = atomicAdd(&cursor[dst[e]], 1);
    csr[p] = src[e];
}

// ---------------------------------------------------------------------------
// Fused pool + final MLP: one block per graph. BN+relu on the fly from
// stats; pooled vector stays in LDS; 2-layer MLP in-block. Zero atomics.
// ---------------------------------------------------------------------------
__global__ __launch_bounds__(256) void pool_final_kernel(
    const short* __restrict__ Cb, const float* __restrict__ stats,
    const float* __restrict__ gamma_p, const float* __restrict__ beta_p,
    const int* __restrict__ batch, const float* __restrict__ Wf1,
    const float* __restrict__ bf1, const float* __restrict__ Wf2,
    const float* __restrict__ bf2, float* __restrict__ out)
{
    __shared__ float sscale[HD];
    __shared__ float sshift[HD];
    __shared__ float red[16][HD];
    __shared__ float gr[HD];
    __shared__ float yr[HD];
    const int t = threadIdx.x;
    if (t < HD) {
        const float invN = 1.f / (float)NN;
        float mean = stats[t] * invN;
        float var = stats[HD + t] * invN - mean * mean;
        float inv = rsqrtf(var + BN_EPS);
        float s = gamma_p[t] * inv;
        sscale[t] = s;
        sshift[t] = beta_p[t] - mean * s;
    }
    __syncthreads();

    const int g = blockIdx.x;
    int lo = 0, hi = NN;
    while (lo < hi) { int m = (lo + hi) >> 1; if (batch[m] < g) lo = m + 1; else hi = m; }
    const int start = lo;
    hi = NN;
    while (lo < hi) { int m = (lo + hi) >> 1; if (batch[m] <= g) lo = m + 1; else hi = m; }
    const int end = lo;

    const int cg = t & 15;   // cols cg*8..cg*8+7
    const int rg = t >> 4;   // row group 0..15
    float sc[8], sh[8];
    #pragma unroll
    for (int i = 0; i < 8; i++) { sc[i] = sscale[cg * 8 + i]; sh[i] = sshift[cg * 8 + i]; }

    float acc[8] = {0, 0, 0, 0, 0, 0, 0, 0};
    for (int r = start + rg; r < end; r += 16) {
        short8v v = *reinterpret_cast<const short8v*>(&Cb[(size_t)r * HD + cg * 8]);
        #pragma unroll
        for (int i = 0; i < 8; i++)
            acc[i] += fmaxf(bf2f(v[i]) * sc[i] + sh[i], 0.f);
    }
    #pragma unroll
    for (int i = 0; i < 8; i++) red[rg][cg * 8 + i] = acc[i];
    __syncthreads();
    if (t < HD) {
        float s = 0.f;
        #pragma unroll
        for (int k = 0; k < 16; k++) s += red[k][t];
        gr[t] = s;
    }
    __syncthreads();
    if (t < HD) {
        float a = bf1[t];
        for (int k = 0; k < HD; k++) a += gr[k] * Wf1[k * HD + t];
        yr[t] = fmaxf(a, 0.f);
    }
    __syncthreads();
    if (t < OUTF) {
        float o = bf2[t];
        for (int k = 0; k < HD; k++) o += yr[k] * Wf2[k * OUTF + t];
        out[g * OUTF + t] = o;
    }
}

// ---------------------------------------------------------------------------
extern "C" void kernel_launch(void* const* d_in, const int* in_sizes, int n_in,
                              void* d_out, int out_size, void* d_ws, size_t ws_size,
                              hipStream_t stream)
{
    const float* x     = (const float*)d_in[0];
    const int*   ei    = (const int*)  d_in[1];
    const int*   batch = (const int*)  d_in[2];
    const float* W1    = (const float*)d_in[3];
    const float* b1    = (const float*)d_in[4];
    const float* W2    = (const float*)d_in[5];
    const float* b2    = (const float*)d_in[6];
    const float* gamma = (const float*)d_in[7];
    const float* beta  = (const float*)d_in[8];
    const float* Wf1   = (const float*)d_in[9];
    const float* bf1   = (const float*)d_in[10];
    const float* Wf2   = (const float*)d_in[11];
    const float* bf2   = (const float*)d_in[12];
    float* out = (float*)d_out;

    float* ws   = (float*)d_ws;
    const size_t BIG = (size_t)NN * HD;       // 6.4M elems
    short* hb  = (short*)ws;                  // bf16 x
    short* CbA = (short*)ws + BIG;            // bf16 pre-BN C, ping
    short* CbB = (short*)ws + 2 * BIG;        // bf16 pre-BN C, pong
    float* smal = ws + 3 * BIG;
    float* stats4 = smal;                     // 4 layers x (sums 128 + sumsq 128)
    int* ip      = (int*)(smal + 65536);
    int* deg     = ip;                        // NN
    int* row_ptr = ip + NN;                   // NN+1
    int* cursor  = row_ptr + NN + 1;          // NN
    int* bsum    = cursor + NN;               // 256
    int* boff    = bsum + 256;                // 256
    int* csr     = boff + 256;                // NE
    short* wpack = (short*)(csr + NE);        // 8 * 16384 bf16

    const int* src = ei;
    const int* dst = ei + NE;

    const int layer_grid = (NN + TR - 1) / TR;    // 1042
    const int cvt_grid  = (NN * 32 + 255) / 256;  // 6250
    const int edge_grid = (NE + 255) / 256;       // 2344

    // ---- one-time per launch: pre-pack (+stats/deg zero) + x->bf16 + CSR ----
    pack_w_kernel<<<64, 256, 0, stream>>>(W1, W2, wpack, stats4, deg);
    cvt_bf16_kernel<<<cvt_grid, 256, 0, stream>>>(x, hb);
    deg_hist_kernel<<<edge_grid, 256, 0, stream>>>(dst, deg);
    scan_partial_kernel<<<NSB, 256, 0, stream>>>(deg, bsum);
    scan_bsums_kernel<<<1, 256, 0, stream>>>(bsum, boff);
    scan_final_kernel<<<NSB, 256, 0, stream>>>(deg, boff, row_ptr, cursor);
    fill_csr_kernel<<<edge_grid, 256, 0, stream>>>(src, dst, cursor, csr);

    // layer inputs alternate: hb -> CbA -> CbB -> CbA -> CbB
    const short* lin[NL + 1] = {hb, CbA, CbB, CbA, CbB};
    for (int l = 0; l < NL; l++) {
        float* sums = stats4 + l * 256;
        if (l == 0) {
            layer_kernel<false><<<layer_grid, 512, 0, stream>>>(
                lin[0], nullptr, nullptr, nullptr, row_ptr, csr,
                wpack + 0 * 16384, b1,
                wpack + 1 * 16384, b2,
                (short*)lin[1], sums, sums + 128);
        } else {
            layer_kernel<true><<<layer_grid, 512, 0, stream>>>(
                lin[l], stats4 + (l - 1) * 256, gamma + (l - 1) * HD, beta + (l - 1) * HD,
                row_ptr, csr,
                wpack + (size_t)(l * 2 + 0) * 16384, b1 + l * HD,
                wpack + (size_t)(l * 2 + 1) * 16384, b2 + l * HD,
                (short*)lin[l + 1], sums, sums + 128);
        }
    }

    pool_final_kernel<<<NG, 256, 0, stream>>>(
        lin[NL], stats4 + 3 * 256, gamma + 3 * HD, beta + 3 * HD, batch,
        Wf1, bf1, Wf2, bf2, out);
}

// Round 19
// 300.559 us; speedup vs baseline: 1.2552x; 1.2552x over previous
//
#include <hip/hip_runtime.h>

#define NN 50000
#define NE 600000
#define HD 128
#define OUTF 64
#define NL 4
#define NG 128
#define BN_EPS 1e-5f
#define NSB 196   // ceil(NN/256) scan blocks

typedef __attribute__((ext_vector_type(8))) short short8v;
typedef __attribute__((ext_vector_type(4))) float float4v;

#define LDSW 136   // padded LDS row stride in bf16 elems

__device__ inline unsigned short f2bf(float f) {   // RNE f32->bf16 (finite inputs)
    unsigned int u = __float_as_uint(f);
    return (unsigned short)((u + 0x7FFF + ((u >> 16) & 1)) >> 16);
}
__device__ inline float bf2f(short s) {
    return __uint_as_float(((unsigned int)(unsigned short)s) << 16);
}

// ---------------------------------------------------------------------------
// W pre-pack + stats zero + deg zero: wpack[w][nt][kb][lane][i].
// ---------------------------------------------------------------------------
__global__ __launch_bounds__(256) void pack_w_kernel(
    const float* __restrict__ W1, const float* __restrict__ W2,
    short* __restrict__ wpack, float* __restrict__ stats4, int* __restrict__ deg)
{
    int gid = blockIdx.x * 256 + threadIdx.x;    // 8*8*4*64 = 16384
    if (gid < 256)
        reinterpret_cast<float4*>(stats4)[gid] = (float4){0.f, 0.f, 0.f, 0.f};
    if (gid < 12500)   // NN/4 exactly
        reinterpret_cast<int4*>(deg)[gid] = (int4){0, 0, 0, 0};
    int l  = gid & 63;
    int kb = (gid >> 6) & 3;
    int nt = (gid >> 8) & 7;
    int w  = gid >> 11;                          // 0..7
    const float* W = (w & 1) ? (W2 + (size_t)(w >> 1) * HD * HD)
                             : (W1 + (size_t)(w >> 1) * HD * HD);
    int col  = nt * 16 + (l & 15);
    int krow = kb * 32 + (l >> 4) * 8;
    short* o = wpack + (size_t)w * 16384 + ((size_t)(nt * 4 + kb) * 64 + l) * 8;
    #pragma unroll
    for (int i = 0; i < 8; i++)
        o[i] = (short)f2bf(W[(size_t)(krow + i) * HD + col]);
}

// x (f32) -> hb (bf16), one-time.
__global__ __launch_bounds__(256) void cvt_bf16_kernel(
    const float* __restrict__ x, short* __restrict__ hb)
{
    int idx = blockIdx.x * 256 + threadIdx.x;
    if (idx >= NN * 32) return;
    float4 v = reinterpret_cast<const float4*>(x)[idx];
    short4 o = make_short4((short)f2bf(v.x), (short)f2bf(v.y),
                           (short)f2bf(v.z), (short)f2bf(v.w));
    reinterpret_cast<short4*>(hb)[idx] = o;
}

// ---------------------------------------------------------------------------
// Fused GIN layer kernel, 64-row tile, 512 threads (8 waves) — R13 body.
// BN applied on the fly during gather from prev-layer stats (2-deep unroll).
// ---------------------------------------------------------------------------
template<bool BN>
__global__ __launch_bounds__(512) void layer_kernel(
    const short* __restrict__ inb, const float* __restrict__ stats_prev,
    const float* __restrict__ gamma_p, const float* __restrict__ beta_p,
    const int* __restrict__ row_ptr, const int* __restrict__ csr,
    const short* __restrict__ wp1, const float* __restrict__ b1,
    const short* __restrict__ wp2, const float* __restrict__ b2,
    short* __restrict__ Cb, float* __restrict__ sums, float* __restrict__ sumsq)
{
    __shared__ __align__(16) short As[64 * LDSW];   // 17408 B
    __shared__ float sscale[HD];
    __shared__ float sshift[HD];
    const int t = threadIdx.x;
    const int row0 = blockIdx.x * 64;

    float sc[8], sh[8];
    const int c8 = (t & 15) * 8;
    if (BN) {
        if (t < HD) {
            const float invN = 1.f / (float)NN;
            float mean = stats_prev[t] * invN;
            float var = stats_prev[HD + t] * invN - mean * mean;
            float inv = rsqrtf(var + BN_EPS);
            float s = gamma_p[t] * inv;
            sscale[t] = s;
            sshift[t] = beta_p[t] - mean * s;
        }
        __syncthreads();
        #pragma unroll
        for (int i = 0; i < 8; i++) { sc[i] = sscale[c8 + i]; sh[i] = sshift[c8 + i]; }
    }

    // ---- 1) gather: 16 lanes/node, 32 nodes/iter, 2 iters, 2-deep unroll ----
    {
        const int ng = t >> 4;          // 0..31
        #pragma unroll
        for (int it = 0; it < 2; it++) {
            int lr = it * 32 + ng;
            int n = row0 + lr;
            float acc[8] = {0, 0, 0, 0, 0, 0, 0, 0};
            if (n < NN) {
                short8v s = *reinterpret_cast<const short8v*>(&inb[(size_t)n * HD + c8]);
                #pragma unroll
                for (int i = 0; i < 8; i++)
                    acc[i] = BN ? fmaxf(bf2f(s[i]) * sc[i] + sh[i], 0.f) : bf2f(s[i]);
                int p = row_ptr[n], pe = row_ptr[n + 1];
                for (; p + 2 <= pe; p += 2) {
                    int s0 = csr[p], s1 = csr[p + 1];
                    short8v a = *reinterpret_cast<const short8v*>(&inb[(size_t)s0 * HD + c8]);
                    short8v b = *reinterpret_cast<const short8v*>(&inb[(size_t)s1 * HD + c8]);
                    if (BN) {
                        #pragma unroll
                        for (int i = 0; i < 8; i++)
                            acc[i] += fmaxf(bf2f(a[i]) * sc[i] + sh[i], 0.f)
                                    + fmaxf(bf2f(b[i]) * sc[i] + sh[i], 0.f);
                    } else {
                        #pragma unroll
                        for (int i = 0; i < 8; i++) acc[i] += bf2f(a[i]) + bf2f(b[i]);
                    }
                }
                if (p < pe) {
                    short8v a = *reinterpret_cast<const short8v*>(&inb[(size_t)csr[p] * HD + c8]);
                    #pragma unroll
                    for (int i = 0; i < 8; i++)
                        acc[i] += BN ? fmaxf(bf2f(a[i]) * sc[i] + sh[i], 0.f) : bf2f(a[i]);
                }
            }
            short8v o;
            #pragma unroll
            for (int i = 0; i < 8; i++) o[i] = (short)f2bf(acc[i]);
            *reinterpret_cast<short8v*>(&As[lr * LDSW + c8]) = o;
        }
    }
    __syncthreads();

    const int wv = t >> 6, l = t & 63;   // wv 0..7
    const int l16 = l & 15, lhi = l >> 4;
    const int wrow = (wv >> 1) * 16;     // 0,16,32,48
    const int nc0 = (wv & 1) * 4;        // 0 or 4

    // ---- 2) MFMA1 ----
    short8v a[4];
    #pragma unroll
    for (int kb = 0; kb < 4; kb++)
        a[kb] = *reinterpret_cast<const short8v*>(&As[(wrow + l16) * LDSW + kb * 32 + lhi * 8]);
    __syncthreads();   // a1-frags in regs; As free for mid

    float4v acc[4];
    #pragma unroll
    for (int q = 0; q < 4; q++) acc[q] = (float4v){0.f, 0.f, 0.f, 0.f};
    {
        const short8v* wp = reinterpret_cast<const short8v*>(wp1);
        #pragma unroll
        for (int q = 0; q < 4; q++) {
            int nt = nc0 + q;
            #pragma unroll
            for (int kb = 0; kb < 4; kb++) {
                short8v b = wp[(nt * 4 + kb) * 64 + l];
                acc[q] = __builtin_amdgcn_mfma_f32_16x16x32_bf16(a[kb], b, acc[q], 0, 0, 0);
            }
        }
    }
    // relu + bf16 -> mid tile back into As
    #pragma unroll
    for (int q = 0; q < 4; q++) {
        int nt = nc0 + q;
        float bnt = b1[nt * 16 + l16];
        #pragma unroll
        for (int j = 0; j < 4; j++) {
            float v = fmaxf(acc[q][j] + bnt, 0.f);
            As[(wrow + lhi * 4 + j) * LDSW + nt * 16 + l16] = (short)f2bf(v);
        }
    }
    __syncthreads();

    // ---- 3) MFMA2 ----
    #pragma unroll
    for (int kb = 0; kb < 4; kb++)
        a[kb] = *reinterpret_cast<const short8v*>(&As[(wrow + l16) * LDSW + kb * 32 + lhi * 8]);

    #pragma unroll
    for (int q = 0; q < 4; q++) acc[q] = (float4v){0.f, 0.f, 0.f, 0.f};
    {
        const short8v* wp = reinterpret_cast<const short8v*>(wp2);
        #pragma unroll
        for (int q = 0; q < 4; q++) {
            int nt = nc0 + q;
            #pragma unroll
            for (int kb = 0; kb < 4; kb++) {
                short8v b = wp[(nt * 4 + kb) * 64 + l];
                acc[q] = __builtin_amdgcn_mfma_f32_16x16x32_bf16(a[kb], b, acc[q], 0, 0, 0);
            }
        }
    }

    // epilogue: bf16 Cb + per-column stats (reuse As as f32 scratch)
    __syncthreads();   // a2-frags consumed; As free
    float* redS = reinterpret_cast<float*>(As);          // [4][128]
    float* redQ = redS + 4 * HD;                         // [4][128]
    #pragma unroll
    for (int q = 0; q < 4; q++) {
        int nt = nc0 + q;
        float bnt = b2[nt * 16 + l16];
        float snt = 0.f, qnt = 0.f;
        #pragma unroll
        for (int j = 0; j < 4; j++) {
            int r = row0 + wrow + lhi * 4 + j;
            if (r < NN) {
                float v = acc[q][j] + bnt;
                Cb[(size_t)r * HD + nt * 16 + l16] = (short)f2bf(v);
                snt += v; qnt += v * v;
            }
        }
        snt += __shfl_xor(snt, 16); snt += __shfl_xor(snt, 32);
        qnt += __shfl_xor(qnt, 16); qnt += __shfl_xor(qnt, 32);
        if (lhi == 0) {
            redS[(wv >> 1) * HD + nt * 16 + l16] = snt;
            redQ[(wv >> 1) * HD + nt * 16 + l16] = qnt;
        }
    }
    __syncthreads();
    if (t < HD) {
        float ss = redS[0 * HD + t] + redS[1 * HD + t] + redS[2 * HD + t] + redS[3 * HD + t];
        float qq = redQ[0 * HD + t] + redQ[1 * HD + t] + redQ[2 * HD + t] + redQ[3 * HD + t];
        atomicAdd(&sums[t], ss);
        atomicAdd(&sumsq[t], qq);
    }
}

// ---------------------------------------------------------------------------
// CSR build: degree histogram -> 3-kernel parallel scan -> slot fill.
// ---------------------------------------------------------------------------
__global__ __launch_bounds__(256) void deg_hist_kernel(
    const int* __restrict__ dst, int* __restrict__ deg)
{
    int e = blockIdx.x * 256 + threadIdx.x;
    if (e < NE) atomicAdd(&deg[dst[e]], 1);
}

__global__ __launch_bounds__(256) void scan_partial_kernel(
    const int* __restrict__ deg, int* __restrict__ bsum)
{
    __shared__ int sd[256];
    int t = threadIdx.x;
    int i = blockIdx.x * 256 + t;
    sd[t] = (i < NN) ? deg[i] : 0;
    __syncthreads();
    for (int o = 128; o > 0; o >>= 1) {
        if (t < o) sd[t] += sd[t + o];
        __syncthreads();
    }
    if (t == 0) bsum[blockIdx.x] = sd[0];
}

__global__ __launch_bounds__(256) void scan_bsums_kernel(
    const int* __restrict__ bsum, int* __restrict__ boff)
{
    __shared__ int sd[256];
    int t = threadIdx.x;
    int v = (t < NSB) ? bsum[t] : 0;
    sd[t] = v;
    __syncthreads();
    for (int o = 1; o < 256; o <<= 1) {
        int x = (t >= o) ? sd[t - o] : 0;
        __syncthreads();
        sd[t] += x;
        __syncthreads();
    }
    if (t < NSB) boff[t] = sd[t] - v;   // exclusive
}

__global__ __launch_bounds__(256) void scan_final_kernel(
    const int* __restrict__ deg, const int* __restrict__ boff,
    int* __restrict__ row_ptr, int* __restrict__ cursor)
{
    __shared__ int sd[256];
    int t = threadIdx.x;
    int i = blockIdx.x * 256 + t;
    int v = (i < NN) ? deg[i] : 0;
    sd[t] = v;
    __syncthreads();
    for (int o = 1; o < 256; o <<= 1) {
        int x = (t >= o) ? sd[t - o] : 0;
        __syncthreads();
        sd[t] += x;
        __syncthreads();
    }
    int excl = sd[t] - v + boff[blockIdx.x];
    if (i < NN) { row_ptr[i] = excl; cursor[i] = excl; }
    if (i == NN - 1) row_ptr[NN] = excl + v;   // == NE
}

__global__ __launch_bounds__(256) void fill_csr_kernel(
    const int* __restrict__ src, const int* __restrict__ dst,
    int* __restrict__ cursor, int* __restrict__ csr)
{
    int e = blockIdx.x * 256 + threadIdx.x;
    if (e >= NE) return;
    int p = atomicAdd(&cursor[dst[e]], 1);
    csr[p] = src[e];
}

// ---------------------------------------------------------------------------
// Fused pool + final MLP: one block per graph. BN+relu on the fly from
// stats; pooled vector stays in LDS; 2-layer MLP in-block. Zero atomics.
// ---------------------------------------------------------------------------
__global__ __launch_bounds__(256) void pool_final_kernel(
    const short* __restrict__ Cb, const float* __restrict__ stats,
    const float* __restrict__ gamma_p, const float* __restrict__ beta_p,
    const int* __restrict__ batch, const float* __restrict__ Wf1,
    const float* __restrict__ bf1, const float* __restrict__ Wf2,
    const float* __restrict__ bf2, float* __restrict__ out)
{
    __shared__ float sscale[HD];
    __shared__ float sshift[HD];
    __shared__ float red[16][HD];
    __shared__ float gr[HD];
    __shared__ float yr[HD];
    const int t = threadIdx.x;
    if (t < HD) {
        const float invN = 1.f / (float)NN;
        float mean = stats[t] * invN;
        float var = stats[HD + t] * invN - mean * mean;
        float inv = rsqrtf(var + BN_EPS);
        float s = gamma_p[t] * inv;
        sscale[t] = s;
        sshift[t] = beta_p[t] - mean * s;
    }
    __syncthreads();

    const int g = blockIdx.x;
    int lo = 0, hi = NN;
    while (lo < hi) { int m = (lo + hi) >> 1; if (batch[m] < g) lo = m + 1; else hi = m; }
    const int start = lo;
    hi = NN;
    while (lo < hi) { int m = (lo + hi) >> 1; if (batch[m] <= g) lo = m + 1; else hi = m; }
    const int end = lo;

    const int cg = t & 15;   // cols cg*8..cg*8+7
    const int rg = t >> 4;   // row group 0..15
    float sc[8], sh[8];
    #pragma unroll
    for (int i = 0; i < 8; i++) { sc[i] = sscale[cg * 8 + i]; sh[i] = sshift[cg * 8 + i]; }

    float acc[8] = {0, 0, 0, 0, 0, 0, 0, 0};
    for (int r = start + rg; r < end; r += 16) {
        short8v v = *reinterpret_cast<const short8v*>(&Cb[(size_t)r * HD + cg * 8]);
        #pragma unroll
        for (int i = 0; i < 8; i++)
            acc[i] += fmaxf(bf2f(v[i]) * sc[i] + sh[i], 0.f);
    }
    #pragma unroll
    for (int i = 0; i < 8; i++) red[rg][cg * 8 + i] = acc[i];
    __syncthreads();
    if (t < HD) {
        float s = 0.f;
        #pragma unroll
        for (int k = 0; k < 16; k++) s += red[k][t];
        gr[t] = s;
    }
    __syncthreads();
    if (t < HD) {
        float a = bf1[t];
        for (int k = 0; k < HD; k++) a += gr[k] * Wf1[k * HD + t];
        yr[t] = fmaxf(a, 0.f);
    }
    __syncthreads();
    if (t < OUTF) {
        float o = bf2[t];
        for (int k = 0; k < HD; k++) o += yr[k] * Wf2[k * OUTF + t];
        out[g * OUTF + t] = o;
    }
}

// ---------------------------------------------------------------------------
extern "C" void kernel_launch(void* const* d_in, const int* in_sizes, int n_in,
                              void* d_out, int out_size, void* d_ws, size_t ws_size,
                              hipStream_t stream)
{
    const float* x     = (const float*)d_in[0];
    const int*   ei    = (const int*)  d_in[1];
    const int*   batch = (const int*)  d_in[2];
    const float* W1    = (const float*)d_in[3];
    const float* b1    = (const float*)d_in[4];
    const float* W2    = (const float*)d_in[5];
    const float* b2    = (const float*)d_in[6];
    const float* gamma = (const float*)d_in[7];
    const float* beta  = (const float*)d_in[8];
    const float* Wf1   = (const float*)d_in[9];
    const float* bf1   = (const float*)d_in[10];
    const float* Wf2   = (const float*)d_in[11];
    const float* bf2   = (const float*)d_in[12];
    float* out = (float*)d_out;

    float* ws   = (float*)d_ws;
    const size_t BIG = (size_t)NN * HD;       // 6.4M elems
    short* hb  = (short*)ws;                  // bf16 x
    short* CbA = (short*)ws + BIG;            // bf16 pre-BN C, ping
    short* CbB = (short*)ws + 2 * BIG;        // bf16 pre-BN C, pong
    float* smal = ws + 3 * BIG;
    float* stats4 = smal;                     // 4 layers x (sums 128 + sumsq 128)
    int* ip      = (int*)(smal + 65536);
    int* deg     = ip;                        // NN
    int* row_ptr = ip + NN;                   // NN+1
    int* cursor  = row_ptr + NN + 1;          // NN
    int* bsum    = cursor + NN;               // 256
    int* boff    = bsum + 256;                // 256
    int* csr     = boff + 256;                // NE
    short* wpack = (short*)(csr + NE);        // 8 * 16384 bf16

    const int* src = ei;
    const int* dst = ei + NE;

    const int layer_grid = (NN + 63) / 64;        // 782
    const int cvt_grid  = (NN * 32 + 255) / 256;  // 6250
    const int edge_grid = (NE + 255) / 256;       // 2344

    // ---- one-time per launch: pre-pack (+stats/deg zero) + x->bf16 + CSR ----
    pack_w_kernel<<<64, 256, 0, stream>>>(W1, W2, wpack, stats4, deg);
    cvt_bf16_kernel<<<cvt_grid, 256, 0, stream>>>(x, hb);
    deg_hist_kernel<<<edge_grid, 256, 0, stream>>>(dst, deg);
    scan_partial_kernel<<<NSB, 256, 0, stream>>>(deg, bsum);
    scan_bsums_kernel<<<1, 256, 0, stream>>>(bsum, boff);
    scan_final_kernel<<<NSB, 256, 0, stream>>>(deg, boff, row_ptr, cursor);
    fill_csr_kernel<<<edge_grid, 256, 0, stream>>>(src, dst, cursor, csr);

    // layer inputs alternate: hb -> CbA -> CbB -> CbA -> CbB
    const short* lin[NL + 1] = {hb, CbA, CbB, CbA, CbB};
    for (int l = 0; l < NL; l++) {
        float* sums = stats4 + l * 256;
        if (l == 0) {
            layer_kernel<false><<<layer_grid, 512, 0, stream>>>(
                lin[0], nullptr, nullptr, nullptr, row_ptr, csr,
                wpack + 0 * 16384, b1,
                wpack + 1 * 16384, b2,
                (short*)lin[1], sums, sums + 128);
        } else {
            layer_kernel<true><<<layer_grid, 512, 0, stream>>>(
                lin[l], stats4 + (l - 1) * 256, gamma + (l - 1) * HD, beta + (l - 1) * HD,
                row_ptr, csr,
                wpack + (size_t)(l * 2 + 0) * 16384, b1 + l * HD,
                wpack + (size_t)(l * 2 + 1) * 16384, b2 + l * HD,
                (short*)lin[l + 1], sums, sums + 128);
        }
    }

    pool_final_kernel<<<NG, 256, 0, stream>>>(
        lin[NL], stats4 + 3 * 256, gamma + 3 * HD, beta + 3 * HD, batch,
        Wf1, bf1, Wf2, bf2, out);
}